// Round 22
// baseline (57.526 us; speedup 1.0000x reference)
//
#include <hip/hip_runtime.h>
#include <math.h>

#define BATCH 4
#define CIN   128
#define CO    64
#define NPIX  4096
#define LOG2E 1.4426950408889634f

typedef unsigned int   uint_t;
typedef unsigned short ushort_t;
typedef __bf16 bfx8 __attribute__((ext_vector_type(8)));
typedef float  f32x4  __attribute__((ext_vector_type(4)));
typedef float  f32x16 __attribute__((ext_vector_type(16)));

#define MFMA(a,b,c)   __builtin_amdgcn_mfma_f32_16x16x32_bf16((a),(b),(c),0,0,0)
#define MFMA32(a,b,c) __builtin_amdgcn_mfma_f32_32x32x16_bf16((a),(b),(c),0,0,0)
#define BC8(x) __builtin_bit_cast(bfx8,(x))

#if __has_builtin(__builtin_amdgcn_exp2f)
#define EXP2(x) __builtin_amdgcn_exp2f(x)
#else
#define EXP2(x) exp2f(x)
#endif

static __device__ __forceinline__ ushort_t f2bf(float f) {
    uint_t u = __builtin_bit_cast(uint_t, f);
    u = (u + 0x7fffu + ((u >> 16) & 1u)) >> 16;   // RNE
    return (ushort_t)u;
}
static __device__ __forceinline__ float bf2f(ushort_t h) {
    return __builtin_bit_cast(float, (uint_t)h << 16);
}
static __device__ __forceinline__ uint_t pk2(float a, float b) {
    return (uint_t)f2bf(a) | ((uint_t)f2bf(b) << 16);
}
static __device__ __forceinline__ uint_t cvtpk(float lo, float hi) {
    uint_t r;
    asm("v_cvt_pk_bf16_f32 %0, %1, %2" : "=v"(r) : "v"(lo), "v"(hi));
    return r;
}
static __device__ __forceinline__ void gload16(const void* g, void* l) {
    __builtin_amdgcn_global_load_lds(
        (const __attribute__((address_space(1))) void*)g,
        (__attribute__((address_space(3))) void*)l, 16, 0, 0);
}

// ---------------- Kernel 0: convert Wf,Wg,Wh,Wa to bf16 in ws ----------------
__global__ __launch_bounds__(256) void wconv_kernel(
    const float* __restrict__ Wf, const float* __restrict__ Wg,
    const float* __restrict__ Wh, const float* __restrict__ Wa,
    ushort_t* __restrict__ Wb)
{
    int gid = blockIdx.x * 256 + threadIdx.x;
    for (int e = gid; e < 28672; e += 4096) {
        float v;
        if      (e < 8192)  v = Wf[e];
        else if (e < 16384) v = Wg[e - 8192];
        else if (e < 24576) v = Wh[e - 16384];
        else                v = Wa[e - 24576];
        Wb[e] = f2bf(v);
    }
}

// ---------------- Kernel 1: MFMA projections, coalesced LDS-staged x ----------------
// R22: replaces R15's 32 strided scalar global loads/thread with coalesced float4 staging
// into xs[128][65] f32 (R1-verified pad-65: both stores and column reads <=2-way = free),
// then conflict-free scalar column reads. Values bit-identical to R15 (same f2bf path).
__global__ __launch_bounds__(256) void proj_kernel(
    const float* __restrict__ x, const ushort_t* __restrict__ Wb,
    const float* __restrict__ bf_, const float* __restrict__ bg_, const float* __restrict__ bh_,
    ushort_t* __restrict__ Q, ushort_t* __restrict__ K, ushort_t* __restrict__ V)
{
    __shared__ float xs[CIN][65];

    int bid = blockIdx.x, b = bid >> 6, n0 = (bid & 63) << 6, t = threadIdx.x;
    int w = t >> 6, lane = t & 63, cl = lane & 15, g = (lane >> 4) & 3;

    const float* xb = x + (size_t)b * CIN * NPIX + n0;
    #pragma unroll
    for (int i = 0; i < 8; ++i) {
        int idx = t + (i << 8);            // 0..2047: row cc, 16B chunk n4
        int cc = idx >> 4, n4 = idx & 15;
        float4 v4 = *(const float4*)(xb + (size_t)cc * NPIX + (n4 << 2));
        float* dst = &xs[cc][n4 << 2];
        dst[0] = v4.x; dst[1] = v4.y; dst[2] = v4.z; dst[3] = v4.w;
    }
    __syncthreads();

    int col = (w << 4) + cl;
    uint4 aq[4];
    #pragma unroll
    for (int ks = 0; ks < 4; ++ks) {
        float v[8];
        #pragma unroll
        for (int j = 0; j < 8; ++j)
            v[j] = xs[(ks << 5) + (g << 3) + j][col];
        uint4 a;
        a.x = pk2(v[0], v[1]);
        a.y = pk2(v[2], v[3]);
        a.z = pk2(v[4], v[5]);
        a.w = pk2(v[6], v[7]);
        aq[ks] = a;
    }

    const float* bps[3] = {bf_, bg_, bh_};
    int nb = n0 + (w << 4);

    for (int p = 0; p < 3; ++p) {
        const ushort_t* Wp = Wb + p * 8192;
        float sc = (p == 0) ? LOG2E : 1.0f;    // fold log2e into Q for exp2 softmax
        f32x4 acc[4];
        #pragma unroll
        for (int ot = 0; ot < 4; ++ot) acc[ot] = (f32x4){0.f,0.f,0.f,0.f};
        #pragma unroll
        for (int ks = 0; ks < 4; ++ks) {
            #pragma unroll
            for (int ot = 0; ot < 4; ++ot) {
                uint4 bq = *(const uint4*)(Wp + (((ot << 4) + cl) << 7) + (ks << 5) + (g << 3));
                acc[ot] = MFMA(BC8(aq[ks]), BC8(bq), acc[ot]);
            }
        }
        if (p < 2) {
            ushort_t* dst = (p == 0 ? Q : K) + ((size_t)b * NPIX + nb) * CO;
            #pragma unroll
            for (int ot = 0; ot < 4; ++ot) {
                float bias = bps[p][(ot << 4) + cl];
                #pragma unroll
                for (int r = 0; r < 4; ++r)
                    dst[(size_t)((g << 2) + r) * CO + (ot << 4) + cl] = f2bf((acc[ot][r] + bias) * sc);
            }
        } else {
            #pragma unroll
            for (int ot = 0; ot < 4; ++ot) {
                float bias = bps[p][(ot << 4) + cl];
                uint2 pk;
                pk.x = pk2(acc[ot][0] + bias, acc[ot][1] + bias);
                pk.y = pk2(acc[ot][2] + bias, acc[ot][3] + bias);
                ushort_t* Vd = V + (size_t)b * CO * NPIX + (size_t)((ot << 4) + cl) * NPIX + nb + (g << 2);
                *(uint2*)Vd = pk;      // STRAIGHT order
            }
        }
    }
}

// ---------------- Kernel 2: flash attention, 32x32 MFMA, register-P (verified R20/R21) ----------------
// 256 blocks, 1024 thr = 16 waves = 2 q-halves (qh=w>>3, 32q) x 8 key-slices (ks=w&7, 32 keys).
// KV tile = 256 keys. QK^T: 4x mfma_32x32x16 with kappa-permuted A-rows; PV: 4x mfma_32x32x16.
// P in registers. Tree-fmax/tree-sum, lane-local lreg with one deferred shfl.
// Split-K merge: TREE. Dynamic LDS 135168B; stats @131072.
__global__ __launch_bounds__(1024, 4) void flash_kernel(
    const ushort_t* __restrict__ Q, const ushort_t* __restrict__ K,
    const ushort_t* __restrict__ V, const ushort_t* __restrict__ Wb,
    const float* __restrict__ ba, const float* __restrict__ gamma,
    float* __restrict__ out)
{
    extern __shared__ __align__(16) char smem[];

    int orig = blockIdx.x;
    int bid = ((orig & 7) << 5) | (orig >> 3);      // XCD swizzle: 2 XCDs per batch
    int b = bid >> 6, n0 = (bid & 63) << 6, t = threadIdx.x;
    int w = t >> 6, lane = t & 63;
    int qh = w >> 3, ks = w & 7;
    int ql = lane & 31, hi = lane >> 5;

    const ushort_t* Qb = Q + ((size_t)b * NPIX + n0) * CO;
    const ushort_t* Kb = K + (size_t)b * NPIX * CO;
    const ushort_t* Vb = V + (size_t)b * CO * NPIX;

    // Q B-fragments: col q = 32qh + ql, k(d) = 16m + 8hi + j
    int q = (qh << 5) + ql;
    uint4 qf[4];
    #pragma unroll
    for (int m = 0; m < 4; ++m)
        qf[m] = *(const uint4*)(Qb + q * CO + (m << 4) + (hi << 3));

    f32x16 oac0 = (f32x16)0.f, oac1 = (f32x16)0.f;  // O[d][q]: row=(p&3)+8(p>>2)+4hi+32dh
    float mreg = -INFINITY, lreg = 0.f;             // lreg is LANE-LOCAL (16-key half-slice)

    // kappa-permuted K A-frag offsets: row r holds key kappa(r) = swap bits2<->3
    int kl = (ql & 19) | ((ql & 4) << 1) | ((ql & 8) >> 1);
    int key = (ks << 5) + kl;
    int koff[4];
    #pragma unroll
    for (int m = 0; m < 4; ++m)
        koff[m] = (key << 7) + (((((m << 1) | hi)) ^ (key & 7)) << 4);
    // V A-frag offsets: row d = 32dh + ql, k(key) = 32ks + 16kt + 8hi + j
    int voff[2][2];
    #pragma unroll
    for (int dh = 0; dh < 2; ++dh)
        #pragma unroll
        for (int kt = 0; kt < 2; ++kt) {
            int dv = (dh << 5) + ql;
            int slot = (((ks << 2) + (kt << 1) + hi)) ^ (dv & 7);
            voff[dh][kt] = 32768 + (dv << 9) + (slot << 4);
        }

    // stage 256-key tile: K 32KB + Vt 32KB; linear LDS dest, pre-swizzled global source
    auto STAGE = [&](char* buf, int kt) {
        #pragma unroll
        for (int i = 0; i < 2; ++i) {
            int cb = (i << 10) + (w << 6);           // wave-uniform chunk base
            int ci = cb | lane;                      // 0..2047
            int kk = ci >> 3, kc = (ci & 7) ^ (kk & 7);
            gload16(Kb + (size_t)((kt << 8) + kk) * CO + (kc << 3), buf + (cb << 4));
            int d = ci >> 5, vc = (ci & 31) ^ (d & 7);
            gload16(Vb + (size_t)d * NPIX + (kt << 8) + (vc << 3), buf + 32768 + (cb << 4));
        }
    };

    auto DOTILE = [&](char* bufc) {
        uint4 kf0 = *(const uint4*)(bufc + koff[0]);
        uint4 kf1 = *(const uint4*)(bufc + koff[1]);
        uint4 kf2 = *(const uint4*)(bufc + koff[2]);
        uint4 kf3 = *(const uint4*)(bufc + koff[3]);
        f32x16 s = (f32x16)0.f;
        __builtin_amdgcn_s_setprio(1);
        s = MFMA32(BC8(kf0), BC8(qf[0]), s);
        s = MFMA32(BC8(kf1), BC8(qf[1]), s);
        s = MFMA32(BC8(kf2), BC8(qf[2]), s);
        s = MFMA32(BC8(kf3), BC8(qf[3]), s);
        __builtin_amdgcn_s_setprio(0);

        // ---- online softmax: 16 scores/lane; tree-fmax (exact reassociation) ----
        float ma0 = fmaxf(s[0],  s[1]),  ma1 = fmaxf(s[2],  s[3]);
        float ma2 = fmaxf(s[4],  s[5]),  ma3 = fmaxf(s[6],  s[7]);
        float ma4 = fmaxf(s[8],  s[9]),  ma5 = fmaxf(s[10], s[11]);
        float ma6 = fmaxf(s[12], s[13]), ma7 = fmaxf(s[14], s[15]);
        float mb0 = fmaxf(ma0, ma1), mb1 = fmaxf(ma2, ma3);
        float mb2 = fmaxf(ma4, ma5), mb3 = fmaxf(ma6, ma7);
        float mx = fmaxf(fmaxf(mb0, mb1), fmaxf(mb2, mb3));
        mx = fmaxf(mx, __shfl_xor(mx, 32));
        if (!__all(mx <= mreg + 11.5f)) {
            float mn = fmaxf(mreg, mx);
            float r  = EXP2(mreg - mn);
            lreg *= r;
            oac0 *= r; oac1 *= r;
            mreg = mn;
        }
        float pv[16];
        #pragma unroll
        for (int p = 0; p < 16; ++p) pv[p] = EXP2(s[p] - mreg);
        // tree-sum (±ulp), lane-local accumulate; cross-lane shfl deferred to after the loop
        float sa0 = pv[0] + pv[1],   sa1 = pv[2] + pv[3];
        float sa2 = pv[4] + pv[5],   sa3 = pv[6] + pv[7];
        float sa4 = pv[8] + pv[9],   sa5 = pv[10] + pv[11];
        float sa6 = pv[12] + pv[13], sa7 = pv[14] + pv[15];
        float sb0 = sa0 + sa1, sb1 = sa2 + sa3, sb2 = sa4 + sa5, sb3 = sa6 + sa7;
        lreg += (sb0 + sb1) + (sb2 + sb3);

        uint4 pb0, pb1;
        pb0.x = cvtpk(pv[0], pv[1]);  pb0.y = cvtpk(pv[2],  pv[3]);
        pb0.z = cvtpk(pv[4], pv[5]);  pb0.w = cvtpk(pv[6],  pv[7]);
        pb1.x = cvtpk(pv[8], pv[9]);  pb1.y = cvtpk(pv[10], pv[11]);
        pb1.z = cvtpk(pv[12], pv[13]); pb1.w = cvtpk(pv[14], pv[15]);

        uint4 vf00 = *(const uint4*)(bufc + voff[0][0]);
        uint4 vf01 = *(const uint4*)(bufc + voff[0][1]);
        uint4 vf10 = *(const uint4*)(bufc + voff[1][0]);
        uint4 vf11 = *(const uint4*)(bufc + voff[1][1]);
        __builtin_amdgcn_s_setprio(1);
        oac0 = MFMA32(BC8(vf00), BC8(pb0), oac0);
        oac0 = MFMA32(BC8(vf01), BC8(pb1), oac0);
        oac1 = MFMA32(BC8(vf10), BC8(pb0), oac1);
        oac1 = MFMA32(BC8(vf11), BC8(pb1), oac1);
        __builtin_amdgcn_s_setprio(0);
    };

    STAGE(smem, 0);
    __syncthreads();
    for (int i = 0; i < 16; ++i) {
        if (i + 1 < 16) STAGE(smem + (((i + 1) & 1) << 16), i + 1);
        DOTILE(smem + ((i & 1) << 16));
        __syncthreads();
    }

    // deferred cross-lane l-sum: mreg was shfl-synced every tile, so scales match
    lreg += __shfl_xor(lreg, 32);

    // ---- stats exchange: mlb/llb [16 waves][32 q] ----
    float* mlb = (float*)(smem + 131072);
    float* llb = (float*)(smem + 133120);
    if (lane < 32) {
        mlb[(w << 5) + lane] = mreg;
        llb[(w << 5) + lane] = lreg;
    }
    __syncthreads();

    float M = -INFINITY;
    float mv[8];
    #pragma unroll
    for (int i = 0; i < 8; ++i) {
        mv[i] = mlb[(((qh << 3) + i) << 5) + ql];
        M = fmaxf(M, mv[i]);
    }
    float L = 0.f;
    #pragma unroll
    for (int i = 0; i < 8; ++i)
        L += EXP2(mv[i] - M) * llb[(((qh << 3) + i) << 5) + ql];
    float fac = EXP2(mreg - M) / L;
    oac0 *= fac; oac1 *= fac;

    // ---- TREE split-K merge: regions r @ r*16384, f32 [64q][64d] swizzled ----
    auto PUT = [&](char* base) {
        #pragma unroll
        for (int dh = 0; dh < 2; ++dh)
            #pragma unroll
            for (int j2 = 0; j2 < 4; ++j2) {
                int slot = (((j2 << 1) + hi + (dh << 3))) ^ (q & 7);
                int off = (q << 8) + (slot << 4);
                f32x4 v;
                if (dh == 0) v = (f32x4){oac0[4*j2], oac0[4*j2+1], oac0[4*j2+2], oac0[4*j2+3]};
                else         v = (f32x4){oac1[4*j2], oac1[4*j2+1], oac1[4*j2+2], oac1[4*j2+3]};
                *(f32x4*)(base + off) = v;
            }
    };
    auto ADD = [&](char* base) {
        #pragma unroll
        for (int dh = 0; dh < 2; ++dh)
            #pragma unroll
            for (int j2 = 0; j2 < 4; ++j2) {
                int slot = (((j2 << 1) + hi + (dh << 3))) ^ (q & 7);
                int off = (q << 8) + (slot << 4);
                f32x4 v = *(const f32x4*)(base + off);
                if (dh == 0) {
                    oac0[4*j2] += v[0]; oac0[4*j2+1] += v[1];
                    oac0[4*j2+2] += v[2]; oac0[4*j2+3] += v[3];
                } else {
                    oac1[4*j2] += v[0]; oac1[4*j2+1] += v[1];
                    oac1[4*j2+2] += v[2]; oac1[4*j2+3] += v[3];
                }
            }
    };

    if (ks >= 4) PUT(smem + ((ks - 4) << 14));       // A: 8 waves publish
    __syncthreads();
    if (ks < 4) ADD(smem + (ks << 14));              // B: ks += ks+4
    __syncthreads();
    if (ks == 2 || ks == 3) PUT(smem + ((ks - 2) << 14));  // C
    __syncthreads();
    if (ks < 2) ADD(smem + (ks << 14));              // D: ks0 += ks2, ks1 += ks3
    __syncthreads();
    if (ks == 1) PUT(smem);                          // E
    __syncthreads();
    // F: ks == 0 holds the full sum -> convert to Pb bf16 [64q][72] pitch 144B @16384
    ushort_t* Pb = (ushort_t*)(smem + 16384);
    if (ks == 0) {
        ADD(smem);
        #pragma unroll
        for (int dh = 0; dh < 2; ++dh)
            #pragma unroll
            for (int j2 = 0; j2 < 4; ++j2) {
                f32x4 v;
                if (dh == 0) v = (f32x4){oac0[4*j2], oac0[4*j2+1], oac0[4*j2+2], oac0[4*j2+3]};
                else         v = (f32x4){oac1[4*j2], oac1[4*j2+1], oac1[4*j2+2], oac1[4*j2+3]};
                uint2 pk;
                pk.x = pk2(v[0], v[1]);
                pk.y = pk2(v[2], v[3]);
                // d0 = 8*j2 + 4*hi + 32*dh -> byte offset d0*2
                *(uint2*)((char*)Pb + q * 144 + (j2 << 4) + (hi << 3) + (dh << 6)) = pk;
            }
    }
    __syncthreads();

    // ---- fused outconv (verified R12/R13): out[o][q] = gamma*(Wa[o][:] . Pb[q][:] + ba[o]) ----
    {
        int c = lane & 15, g = (lane >> 4) & 3;
        const ushort_t* Wab = Wb + 24576;
        float gm = gamma[0];
        int ot = w >> 2, qt3 = w & 3;
        f32x4 acc2 = (f32x4){0.f,0.f,0.f,0.f};
        #pragma unroll
        for (int k2 = 0; k2 < 2; ++k2) {
            uint4 af  = *(const uint4*)(Wab + (((ot << 4) + c) << 6) + (k2 << 5) + (g << 3));
            uint4 pfq = *(const uint4*)((char*)Pb + (((qt3 << 4) + c)) * 144 + (k2 << 6) + (g << 4));
            acc2 = MFMA(BC8(af), BC8(pfq), acc2);
        }
        float* ob = out + (size_t)b * CO * NPIX + n0;
        #pragma unroll
        for (int r = 0; r < 4; ++r) {
            int o = (ot << 4) + (g << 2) + r;
            ob[(size_t)o * NPIX + (qt3 << 4) + c] = gm * (acc2[r] + ba[o]);
        }
    }
}

extern "C" void kernel_launch(void* const* d_in, const int* in_sizes, int n_in,
                              void* d_out, int out_size, void* d_ws, size_t ws_size,
                              hipStream_t stream) {
    const float* x     = (const float*)d_in[0];
    const float* Wf    = (const float*)d_in[1];
    const float* bf_   = (const float*)d_in[2];
    const float* Wg    = (const float*)d_in[3];
    const float* bg_   = (const float*)d_in[4];
    const float* Wh    = (const float*)d_in[5];
    const float* bh_   = (const float*)d_in[6];
    const float* Wa    = (const float*)d_in[7];
    const float* ba    = (const float*)d_in[8];
    const float* gamma = (const float*)d_in[9];
    float* out = (float*)d_out;

    ushort_t* Wb = (ushort_t*)d_ws;                               // 57344 B
    const size_t matb = (size_t)BATCH * NPIX * CO;                // 1M elems
    ushort_t* Q = (ushort_t*)((char*)d_ws + 65536);               // 2 MB
    ushort_t* K = Q + matb;                                       // 2 MB
    ushort_t* V = K + matb;                                       // 2 MB (transposed [B][64][N], straight)

    wconv_kernel<<<16, 256, 0, stream>>>(Wf, Wg, Wh, Wa, Wb);
    proj_kernel<<<BATCH * (NPIX / 64), 256, 0, stream>>>(x, Wb, bf_, bg_, bh_, Q, K, V);
    flash_kernel<<<BATCH * (NPIX / 64), 1024, 135168, stream>>>(Q, K, V, Wb, ba, gamma, out);
}

// Round 23
// 52.547 us; speedup vs baseline: 1.0948x; 1.0948x over previous
//
#include <hip/hip_runtime.h>
#include <math.h>

#define BATCH 4
#define CIN   128
#define CO    64
#define NPIX  4096
#define LOG2E 1.4426950408889634f

typedef unsigned int   uint_t;
typedef unsigned short ushort_t;
typedef __bf16 bfx8 __attribute__((ext_vector_type(8)));
typedef float  f32x4  __attribute__((ext_vector_type(4)));
typedef float  f32x16 __attribute__((ext_vector_type(16)));

#define MFMA(a,b,c)   __builtin_amdgcn_mfma_f32_16x16x32_bf16((a),(b),(c),0,0,0)
#define MFMA32(a,b,c) __builtin_amdgcn_mfma_f32_32x32x16_bf16((a),(b),(c),0,0,0)
#define BC8(x) __builtin_bit_cast(bfx8,(x))

#if __has_builtin(__builtin_amdgcn_exp2f)
#define EXP2(x) __builtin_amdgcn_exp2f(x)
#else
#define EXP2(x) exp2f(x)
#endif

static __device__ __forceinline__ ushort_t f2bf(float f) {
    uint_t u = __builtin_bit_cast(uint_t, f);
    u = (u + 0x7fffu + ((u >> 16) & 1u)) >> 16;   // RNE
    return (ushort_t)u;
}
static __device__ __forceinline__ float bf2f(ushort_t h) {
    return __builtin_bit_cast(float, (uint_t)h << 16);
}
static __device__ __forceinline__ uint_t pk2(float a, float b) {
    return (uint_t)f2bf(a) | ((uint_t)f2bf(b) << 16);
}
static __device__ __forceinline__ uint_t cvtpk(float lo, float hi) {
    uint_t r;
    asm("v_cvt_pk_bf16_f32 %0, %1, %2" : "=v"(r) : "v"(lo), "v"(hi));
    return r;
}
static __device__ __forceinline__ void gload16(const void* g, void* l) {
    __builtin_amdgcn_global_load_lds(
        (const __attribute__((address_space(1))) void*)g,
        (__attribute__((address_space(3))) void*)l, 16, 0, 0);
}

// ---------------- Kernel 0: convert Wf,Wg,Wh,Wa to bf16 in ws ----------------
__global__ __launch_bounds__(256) void wconv_kernel(
    const float* __restrict__ Wf, const float* __restrict__ Wg,
    const float* __restrict__ Wh, const float* __restrict__ Wa,
    ushort_t* __restrict__ Wb)
{
    int gid = blockIdx.x * 256 + threadIdx.x;
    for (int e = gid; e < 28672; e += 4096) {
        float v;
        if      (e < 8192)  v = Wf[e];
        else if (e < 16384) v = Wg[e - 8192];
        else if (e < 24576) v = Wh[e - 16384];
        else                v = Wa[e - 24576];
        Wb[e] = f2bf(v);
    }
}

// ---------------- Kernel 1: MFMA projections, LDS-free, plain-bf16 x (verified R14/R15) ----------------
__global__ __launch_bounds__(256) void proj_kernel(
    const float* __restrict__ x, const ushort_t* __restrict__ Wb,
    const float* __restrict__ bf_, const float* __restrict__ bg_, const float* __restrict__ bh_,
    ushort_t* __restrict__ Q, ushort_t* __restrict__ K, ushort_t* __restrict__ V)
{
    int bid = blockIdx.x, b = bid >> 6, n0 = (bid & 63) << 6, t = threadIdx.x;
    int w = t >> 6, lane = t & 63, cl = lane & 15, g = (lane >> 4) & 3;

    const float* xcol = x + (size_t)b * CIN * NPIX + n0 + (w << 4) + cl;

    uint4 aq[4];
    #pragma unroll
    for (int ks = 0; ks < 4; ++ks) {
        float v[8];
        #pragma unroll
        for (int j = 0; j < 8; ++j)
            v[j] = xcol[(size_t)((ks << 5) + (g << 3) + j) * NPIX];
        uint4 a;
        a.x = pk2(v[0], v[1]);
        a.y = pk2(v[2], v[3]);
        a.z = pk2(v[4], v[5]);
        a.w = pk2(v[6], v[7]);
        aq[ks] = a;
    }

    const float* bps[3] = {bf_, bg_, bh_};
    int nb = n0 + (w << 4);

    for (int p = 0; p < 3; ++p) {
        const ushort_t* Wp = Wb + p * 8192;
        float sc = (p == 0) ? LOG2E : 1.0f;    // fold log2e into Q for exp2 softmax
        f32x4 acc[4];
        #pragma unroll
        for (int ot = 0; ot < 4; ++ot) acc[ot] = (f32x4){0.f,0.f,0.f,0.f};
        #pragma unroll
        for (int ks = 0; ks < 4; ++ks) {
            #pragma unroll
            for (int ot = 0; ot < 4; ++ot) {
                uint4 bq = *(const uint4*)(Wp + (((ot << 4) + cl) << 7) + (ks << 5) + (g << 3));
                acc[ot] = MFMA(BC8(aq[ks]), BC8(bq), acc[ot]);
            }
        }
        if (p < 2) {
            ushort_t* dst = (p == 0 ? Q : K) + ((size_t)b * NPIX + nb) * CO;
            #pragma unroll
            for (int ot = 0; ot < 4; ++ot) {
                float bias = bps[p][(ot << 4) + cl];
                #pragma unroll
                for (int r = 0; r < 4; ++r)
                    dst[(size_t)((g << 2) + r) * CO + (ot << 4) + cl] = f2bf((acc[ot][r] + bias) * sc);
            }
        } else {
            #pragma unroll
            for (int ot = 0; ot < 4; ++ot) {
                float bias = bps[p][(ot << 4) + cl];
                uint2 pk;
                pk.x = pk2(acc[ot][0] + bias, acc[ot][1] + bias);
                pk.y = pk2(acc[ot][2] + bias, acc[ot][3] + bias);
                ushort_t* Vd = V + (size_t)b * CO * NPIX + (size_t)((ot << 4) + cl) * NPIX + nb + (g << 2);
                *(uint2*)Vd = pk;      // STRAIGHT order
            }
        }
    }
}

// ---------------- Kernel 2: flash attention, 32x32 MFMA, register-P (R20 + chain cuts) ----------------
// 256 blocks, 1024 thr = 16 waves = 2 q-halves (qh=w>>3, 32q) x 8 key-slices (ks=w&7, 32 keys).
// KV tile = 256 keys. QK^T: 4x mfma_32x32x16 with kappa-permuted A-rows; PV: 4x mfma_32x32x16.
// P in registers. Tree-fmax (exact), tree-sum (±ulp), lane-local lreg with ONE deferred shfl.
// Split-K merge: TREE (R20-verified). Dynamic LDS 135168B; stats @131072.
__global__ __launch_bounds__(1024, 4) void flash_kernel(
    const ushort_t* __restrict__ Q, const ushort_t* __restrict__ K,
    const ushort_t* __restrict__ V, const ushort_t* __restrict__ Wb,
    const float* __restrict__ ba, const float* __restrict__ gamma,
    float* __restrict__ out)
{
    extern __shared__ __align__(16) char smem[];

    int orig = blockIdx.x;
    int bid = ((orig & 7) << 5) | (orig >> 3);      // XCD swizzle: 2 XCDs per batch
    int b = bid >> 6, n0 = (bid & 63) << 6, t = threadIdx.x;
    int w = t >> 6, lane = t & 63;
    int qh = w >> 3, ks = w & 7;
    int ql = lane & 31, hi = lane >> 5;

    const ushort_t* Qb = Q + ((size_t)b * NPIX + n0) * CO;
    const ushort_t* Kb = K + (size_t)b * NPIX * CO;
    const ushort_t* Vb = V + (size_t)b * CO * NPIX;

    // Q B-fragments: col q = 32qh + ql, k(d) = 16m + 8hi + j
    int q = (qh << 5) + ql;
    uint4 qf[4];
    #pragma unroll
    for (int m = 0; m < 4; ++m)
        qf[m] = *(const uint4*)(Qb + q * CO + (m << 4) + (hi << 3));

    f32x16 oac0 = (f32x16)0.f, oac1 = (f32x16)0.f;  // O[d][q]: row=(p&3)+8(p>>2)+4hi+32dh
    float mreg = -INFINITY, lreg = 0.f;             // lreg is LANE-LOCAL (16-key half-slice)

    // kappa-permuted K A-frag offsets: row r holds key kappa(r) = swap bits2<->3
    int kl = (ql & 19) | ((ql & 4) << 1) | ((ql & 8) >> 1);
    int key = (ks << 5) + kl;
    int koff[4];
    #pragma unroll
    for (int m = 0; m < 4; ++m)
        koff[m] = (key << 7) + (((((m << 1) | hi)) ^ (key & 7)) << 4);
    // V A-frag offsets: row d = 32dh + ql, k(key) = 32ks + 16kt + 8hi + j
    int voff[2][2];
    #pragma unroll
    for (int dh = 0; dh < 2; ++dh)
        #pragma unroll
        for (int kt = 0; kt < 2; ++kt) {
            int dv = (dh << 5) + ql;
            int slot = (((ks << 2) + (kt << 1) + hi)) ^ (dv & 7);
            voff[dh][kt] = 32768 + (dv << 9) + (slot << 4);
        }

    // stage 256-key tile: K 32KB + Vt 32KB; linear LDS dest, pre-swizzled global source
    auto STAGE = [&](char* buf, int kt) {
        #pragma unroll
        for (int i = 0; i < 2; ++i) {
            int cb = (i << 10) + (w << 6);           // wave-uniform chunk base
            int ci = cb | lane;                      // 0..2047
            int kk = ci >> 3, kc = (ci & 7) ^ (kk & 7);
            gload16(Kb + (size_t)((kt << 8) + kk) * CO + (kc << 3), buf + (cb << 4));
            int d = ci >> 5, vc = (ci & 31) ^ (d & 7);
            gload16(Vb + (size_t)d * NPIX + (kt << 8) + (vc << 3), buf + 32768 + (cb << 4));
        }
    };

    auto DOTILE = [&](char* bufc) {
        uint4 kf0 = *(const uint4*)(bufc + koff[0]);
        uint4 kf1 = *(const uint4*)(bufc + koff[1]);
        uint4 kf2 = *(const uint4*)(bufc + koff[2]);
        uint4 kf3 = *(const uint4*)(bufc + koff[3]);
        f32x16 s = (f32x16)0.f;
        __builtin_amdgcn_s_setprio(1);
        s = MFMA32(BC8(kf0), BC8(qf[0]), s);
        s = MFMA32(BC8(kf1), BC8(qf[1]), s);
        s = MFMA32(BC8(kf2), BC8(qf[2]), s);
        s = MFMA32(BC8(kf3), BC8(qf[3]), s);
        __builtin_amdgcn_s_setprio(0);

        // ---- online softmax: 16 scores/lane; tree-fmax (exact reassociation) ----
        float ma0 = fmaxf(s[0],  s[1]),  ma1 = fmaxf(s[2],  s[3]);
        float ma2 = fmaxf(s[4],  s[5]),  ma3 = fmaxf(s[6],  s[7]);
        float ma4 = fmaxf(s[8],  s[9]),  ma5 = fmaxf(s[10], s[11]);
        float ma6 = fmaxf(s[12], s[13]), ma7 = fmaxf(s[14], s[15]);
        float mb0 = fmaxf(ma0, ma1), mb1 = fmaxf(ma2, ma3);
        float mb2 = fmaxf(ma4, ma5), mb3 = fmaxf(ma6, ma7);
        float mx = fmaxf(fmaxf(mb0, mb1), fmaxf(mb2, mb3));
        mx = fmaxf(mx, __shfl_xor(mx, 32));
        if (!__all(mx <= mreg + 11.5f)) {
            float mn = fmaxf(mreg, mx);
            float r  = EXP2(mreg - mn);
            lreg *= r;
            oac0 *= r; oac1 *= r;
            mreg = mn;
        }
        float pv[16];
        #pragma unroll
        for (int p = 0; p < 16; ++p) pv[p] = EXP2(s[p] - mreg);
        // tree-sum (±ulp), lane-local accumulate; cross-lane shfl deferred to after the loop
        float sa0 = pv[0] + pv[1],   sa1 = pv[2] + pv[3];
        float sa2 = pv[4] + pv[5],   sa3 = pv[6] + pv[7];
        float sa4 = pv[8] + pv[9],   sa5 = pv[10] + pv[11];
        float sa6 = pv[12] + pv[13], sa7 = pv[14] + pv[15];
        float sb0 = sa0 + sa1, sb1 = sa2 + sa3, sb2 = sa4 + sa5, sb3 = sa6 + sa7;
        lreg += (sb0 + sb1) + (sb2 + sb3);

        uint4 pb0, pb1;
        pb0.x = cvtpk(pv[0], pv[1]);  pb0.y = cvtpk(pv[2],  pv[3]);
        pb0.z = cvtpk(pv[4], pv[5]);  pb0.w = cvtpk(pv[6],  pv[7]);
        pb1.x = cvtpk(pv[8], pv[9]);  pb1.y = cvtpk(pv[10], pv[11]);
        pb1.z = cvtpk(pv[12], pv[13]); pb1.w = cvtpk(pv[14], pv[15]);

        uint4 vf00 = *(const uint4*)(bufc + voff[0][0]);
        uint4 vf01 = *(const uint4*)(bufc + voff[0][1]);
        uint4 vf10 = *(const uint4*)(bufc + voff[1][0]);
        uint4 vf11 = *(const uint4*)(bufc + voff[1][1]);
        __builtin_amdgcn_s_setprio(1);
        oac0 = MFMA32(BC8(vf00), BC8(pb0), oac0);
        oac0 = MFMA32(BC8(vf01), BC8(pb1), oac0);
        oac1 = MFMA32(BC8(vf10), BC8(pb0), oac1);
        oac1 = MFMA32(BC8(vf11), BC8(pb1), oac1);
        __builtin_amdgcn_s_setprio(0);
    };

    STAGE(smem, 0);
    __syncthreads();
    for (int i = 0; i < 16; ++i) {
        if (i + 1 < 16) STAGE(smem + (((i + 1) & 1) << 16), i + 1);
        DOTILE(smem + ((i & 1) << 16));
        __syncthreads();
    }

    // deferred cross-lane l-sum: mreg was shfl-synced every tile, so scales match
    lreg += __shfl_xor(lreg, 32);

    // ---- stats exchange: mlb/llb [16 waves][32 q] ----
    float* mlb = (float*)(smem + 131072);
    float* llb = (float*)(smem + 133120);
    if (lane < 32) {
        mlb[(w << 5) + lane] = mreg;
        llb[(w << 5) + lane] = lreg;
    }
    __syncthreads();

    float M = -INFINITY;
    float mv[8];
    #pragma unroll
    for (int i = 0; i < 8; ++i) {
        mv[i] = mlb[(((qh << 3) + i) << 5) + ql];
        M = fmaxf(M, mv[i]);
    }
    float L = 0.f;
    #pragma unroll
    for (int i = 0; i < 8; ++i)
        L += EXP2(mv[i] - M) * llb[(((qh << 3) + i) << 5) + ql];
    float fac = EXP2(mreg - M) / L;
    oac0 *= fac; oac1 *= fac;

    // ---- TREE split-K merge: regions r @ r*16384, f32 [64q][64d] swizzled ----
    auto PUT = [&](char* base) {
        #pragma unroll
        for (int dh = 0; dh < 2; ++dh)
            #pragma unroll
            for (int j2 = 0; j2 < 4; ++j2) {
                int slot = (((j2 << 1) + hi + (dh << 3))) ^ (q & 7);
                int off = (q << 8) + (slot << 4);
                f32x4 v;
                if (dh == 0) v = (f32x4){oac0[4*j2], oac0[4*j2+1], oac0[4*j2+2], oac0[4*j2+3]};
                else         v = (f32x4){oac1[4*j2], oac1[4*j2+1], oac1[4*j2+2], oac1[4*j2+3]};
                *(f32x4*)(base + off) = v;
            }
    };
    auto ADD = [&](char* base) {
        #pragma unroll
        for (int dh = 0; dh < 2; ++dh)
            #pragma unroll
            for (int j2 = 0; j2 < 4; ++j2) {
                int slot = (((j2 << 1) + hi + (dh << 3))) ^ (q & 7);
                int off = (q << 8) + (slot << 4);
                f32x4 v = *(const f32x4*)(base + off);
                if (dh == 0) {
                    oac0[4*j2] += v[0]; oac0[4*j2+1] += v[1];
                    oac0[4*j2+2] += v[2]; oac0[4*j2+3] += v[3];
                } else {
                    oac1[4*j2] += v[0]; oac1[4*j2+1] += v[1];
                    oac1[4*j2+2] += v[2]; oac1[4*j2+3] += v[3];
                }
            }
    };

    if (ks >= 4) PUT(smem + ((ks - 4) << 14));       // A: 8 waves publish
    __syncthreads();
    if (ks < 4) ADD(smem + (ks << 14));              // B: ks += ks+4
    __syncthreads();
    if (ks == 2 || ks == 3) PUT(smem + ((ks - 2) << 14));  // C
    __syncthreads();
    if (ks < 2) ADD(smem + (ks << 14));              // D: ks0 += ks2, ks1 += ks3
    __syncthreads();
    if (ks == 1) PUT(smem);                          // E
    __syncthreads();
    // F: ks == 0 holds the full sum -> convert to Pb bf16 [64q][72] pitch 144B @16384
    ushort_t* Pb = (ushort_t*)(smem + 16384);
    if (ks == 0) {
        ADD(smem);
        #pragma unroll
        for (int dh = 0; dh < 2; ++dh)
            #pragma unroll
            for (int j2 = 0; j2 < 4; ++j2) {
                f32x4 v;
                if (dh == 0) v = (f32x4){oac0[4*j2], oac0[4*j2+1], oac0[4*j2+2], oac0[4*j2+3]};
                else         v = (f32x4){oac1[4*j2], oac1[4*j2+1], oac1[4*j2+2], oac1[4*j2+3]};
                uint2 pk;
                pk.x = pk2(v[0], v[1]);
                pk.y = pk2(v[2], v[3]);
                // d0 = 8*j2 + 4*hi + 32*dh -> byte offset d0*2
                *(uint2*)((char*)Pb + q * 144 + (j2 << 4) + (hi << 3) + (dh << 6)) = pk;
            }
    }
    __syncthreads();

    // ---- fused outconv (verified R12/R13): out[o][q] = gamma*(Wa[o][:] . Pb[q][:] + ba[o]) ----
    {
        int c = lane & 15, g = (lane >> 4) & 3;
        const ushort_t* Wab = Wb + 24576;
        float gm = gamma[0];
        int ot = w >> 2, qt3 = w & 3;
        f32x4 acc2 = (f32x4){0.f,0.f,0.f,0.f};
        #pragma unroll
        for (int k2 = 0; k2 < 2; ++k2) {
            uint4 af  = *(const uint4*)(Wab + (((ot << 4) + c) << 6) + (k2 << 5) + (g << 3));
            uint4 pfq = *(const uint4*)((char*)Pb + (((qt3 << 4) + c)) * 144 + (k2 << 6) + (g << 4));
            acc2 = MFMA(BC8(af), BC8(pfq), acc2);
        }
        float* ob = out + (size_t)b * CO * NPIX + n0;
        #pragma unroll
        for (int r = 0; r < 4; ++r) {
            int o = (ot << 4) + (g << 2) + r;
            ob[(size_t)o * NPIX + (qt3 << 4) + c] = gm * (acc2[r] + ba[o]);
        }
    }
}

extern "C" void kernel_launch(void* const* d_in, const int* in_sizes, int n_in,
                              void* d_out, int out_size, void* d_ws, size_t ws_size,
                              hipStream_t stream) {
    const float* x     = (const float*)d_in[0];
    const float* Wf    = (const float*)d_in[1];
    const float* bf_   = (const float*)d_in[2];
    const float* Wg    = (const float*)d_in[3];
    const float* bg_   = (const float*)d_in[4];
    const float* Wh    = (const float*)d_in[5];
    const float* bh_   = (const float*)d_in[6];
    const float* Wa    = (const float*)d_in[7];
    const float* ba    = (const float*)d_in[8];
    const float* gamma = (const float*)d_in[9];
    float* out = (float*)d_out;

    ushort_t* Wb = (ushort_t*)d_ws;                               // 57344 B
    const size_t matb = (size_t)BATCH * NPIX * CO;                // 1M elems
    ushort_t* Q = (ushort_t*)((char*)d_ws + 65536);               // 2 MB
    ushort_t* K = Q + matb;                                       // 2 MB
    ushort_t* V = K + matb;                                       // 2 MB (transposed [B][64][N], straight)

    wconv_kernel<<<16, 256, 0, stream>>>(Wf, Wg, Wh, Wa, Wb);
    proj_kernel<<<BATCH * (NPIX / 64), 256, 0, stream>>>(x, Wb, bf_, bg_, bh_, Q, K, V);
    flash_kernel<<<BATCH * (NPIX / 64), 1024, 135168, stream>>>(Q, K, V, Wb, ba, gamma, out);
}